// Round 1
// baseline (205.302 us; speedup 1.0000x reference)
//
#include <hip/hip_runtime.h>
#include <math.h>

#define S_N   100000
#define K_N   30
#define N_OUT 1024
#define BB    4096
// ws layout (bytes):
//  FM : [1024][8] f32      @ 0          (32 KiB)
//  C  : [4096][1024] f32   @ 32768      (16 MiB)
//  h1 : [4096][256] f32    @ after C    (4 MiB)
//  h2 : [4096][128] f32    @ after h1   (2 MiB)

// ---------------------------------------------------------------------------
// FM = min(chi-derived 7-vector, 1).T   (1024 x 7, padded to 8)
// ---------------------------------------------------------------------------
__global__ __launch_bounds__(256) void cicdm_fm_kernel(
    const float* __restrict__ fm_vars, float* __restrict__ FM) {
  int n = blockIdx.x * 256 + threadIdx.x;
  if (n >= N_OUT) return;
  float c0 = fabsf(fm_vars[0 * N_OUT + n]);
  float c1 = fabsf(fm_vars[1 * N_OUT + n]);
  float c2 = fabsf(fm_vars[2 * N_OUT + n]);
  float c3 = fabsf(fm_vars[3 * N_OUT + n]);
  float c4 = fabsf(fm_vars[4 * N_OUT + n]);
  float c5 = fabsf(fm_vars[5 * N_OUT + n]);
  float f0 = c0;
  float f1 = c1;
  float f2 = fmaxf(f0, f1) + c2;
  float f3 = c3;
  float f4 = fmaxf(f3, f0) + c4;
  float f5 = fmaxf(f3, f1) + c5;
  FM[n * 8 + 0] = fminf(f0, 1.f);
  FM[n * 8 + 1] = fminf(f1, 1.f);
  FM[n * 8 + 2] = fminf(f2, 1.f);
  FM[n * 8 + 3] = fminf(f3, 1.f);
  FM[n * 8 + 4] = fminf(f4, 1.f);
  FM[n * 8 + 5] = fminf(f5, 1.f);
  FM[n * 8 + 6] = 1.f;
  FM[n * 8 + 7] = 0.f;
}

// ---------------------------------------------------------------------------
// Fused gather + sigmoid + stable-3-sort Choquet aggregation.
// One block per batch row. sel row (30 floats) lives in LDS.
// ---------------------------------------------------------------------------
__global__ __launch_bounds__(256) void cicdm_choquet_kernel(
    const int* __restrict__ stu_id, const int* __restrict__ q_idx,
    const float* __restrict__ emb, const float* __restrict__ FM,
    float* __restrict__ C) {
  __shared__ float s[K_N];
  const int b = blockIdx.x;
  const int tid = threadIdx.x;
  if (tid < K_N) {
    float x = emb[(long)stu_id[b] * K_N + tid];
    s[tid] = 1.f / (1.f + expf(-x));
  }
  __syncthreads();
  for (int n = tid; n < N_OUT; n += 256) {
    int q0 = q_idx[n * 3 + 0];
    int q1 = q_idx[n * 3 + 1];
    int q2 = q_idx[n * 3 + 2];
    float v0 = s[q0], v1 = s[q1], v2 = s[q2];
    // stable descending argsort of (v0,v1,v2): rank = #elements strictly
    // before me; ties broken by original index (lower index first).
    bool c01 = v1 > v0, c02 = v2 > v0, c12 = v2 > v1;
    int r0 = (int)c01 + (int)c02;
    int r1 = (int)(!c01) + (int)c12;
    int p0 = (r0 == 0) ? 0 : ((r1 == 0) ? 1 : 2);  // index of largest
    int p1 = (r0 == 1) ? 0 : ((r1 == 1) ? 1 : 2);  // index of middle
    int p2 = 3 - p0 - p1;                          // index of smallest
    float sv0 = (p0 == 0) ? v0 : ((p0 == 1) ? v1 : v2);
    float sv1 = (p1 == 0) ? v0 : ((p1 == 1) ? v1 : v2);
    float sv2 = (p2 == 0) ? v0 : ((p2 == 1) ? v1 : v2);
    int o0 = (1 << p0) - 1;              // in {0,1,3}
    int o1 = (1 << p0) + (1 << p1) - 1;  // in {2,4,5}
    float fm0 = FM[n * 8 + o0];
    float fm1 = FM[n * 8 + o1];
    // o2 == 6 always, FM[n][6] == 1
    C[(long)b * N_OUT + n] = (sv0 - sv1) * fm0 + (sv1 - sv2) * fm1 + sv2;
  }
}

// ---------------------------------------------------------------------------
// Tiled f32 GEMM: out[M][N] = act(A[M][K] @ W[N][K]^T + bias), row-major.
// ACT: 0 = relu, 1 = sigmoid.
// ---------------------------------------------------------------------------
template <int BM, int BN, int BK, int TM, int TN, int ACT>
__global__ __launch_bounds__(256) void cicdm_gemm_kernel(
    const float* __restrict__ A, const float* __restrict__ W,
    const float* __restrict__ bias, float* __restrict__ out,
    int M, int N, int K) {
  constexpr int NT = (BM / TM) * (BN / TN);
  static_assert(NT == 256, "block must be 256 threads");
  __shared__ float As[BK][BM + 4];
  __shared__ float Bs[BK][BN + 4];
  const int tid = threadIdx.x;
  const int tx = tid % (BN / TN);
  const int ty = tid / (BN / TN);
  const int bm = blockIdx.y * BM;
  const int bn = blockIdx.x * BN;

  float acc[TM][TN] = {};

  for (int k0 = 0; k0 < K; k0 += BK) {
    // stage A tile (transposed into LDS), float4 global loads
#pragma unroll
    for (int i = tid; i < BM * BK / 4; i += NT) {
      int row = i / (BK / 4);
      int c = i % (BK / 4);
      float4 v = *reinterpret_cast<const float4*>(
          &A[(long)(bm + row) * K + k0 + c * 4]);
      As[c * 4 + 0][row] = v.x;
      As[c * 4 + 1][row] = v.y;
      As[c * 4 + 2][row] = v.z;
      As[c * 4 + 3][row] = v.w;
    }
    // stage W tile (transposed into LDS)
#pragma unroll
    for (int i = tid; i < BN * BK / 4; i += NT) {
      int row = i / (BK / 4);
      int c = i % (BK / 4);
      float4 v = *reinterpret_cast<const float4*>(
          &W[(long)(bn + row) * K + k0 + c * 4]);
      Bs[c * 4 + 0][row] = v.x;
      Bs[c * 4 + 1][row] = v.y;
      Bs[c * 4 + 2][row] = v.z;
      Bs[c * 4 + 3][row] = v.w;
    }
    __syncthreads();
#pragma unroll
    for (int kk = 0; kk < BK; ++kk) {
      float a[TM], bv[TN];
#pragma unroll
      for (int i = 0; i < TM; ++i) a[i] = As[kk][ty * TM + i];
#pragma unroll
      for (int j = 0; j < TN; ++j) bv[j] = Bs[kk][tx * TN + j];
#pragma unroll
      for (int i = 0; i < TM; ++i)
#pragma unroll
        for (int j = 0; j < TN; ++j)
          acc[i][j] = fmaf(a[i], bv[j], acc[i][j]);
    }
    __syncthreads();
  }

#pragma unroll
  for (int i = 0; i < TM; ++i) {
    int row = bm + ty * TM + i;
#pragma unroll
    for (int j = 0; j < TN; ++j) {
      int col = bn + tx * TN + j;
      float v = acc[i][j] + bias[col];
      if (ACT == 0) {
        v = fmaxf(v, 0.f);
      } else {
        v = 1.f / (1.f + expf(-v));
      }
      out[(long)row * N + col] = v;
    }
  }
}

// ---------------------------------------------------------------------------
extern "C" void kernel_launch(void* const* d_in, const int* in_sizes, int n_in,
                              void* d_out, int out_size, void* d_ws,
                              size_t ws_size, hipStream_t stream) {
  const int* stu_id = (const int*)d_in[0];
  // d_in[1] = exer_id (unused by reference), d_in[2] = kn_emb (unused)
  const int* q_idx = (const int*)d_in[3];
  const float* emb = (const float*)d_in[4];
  const float* fm_vars = (const float*)d_in[5];
  const float* w1 = (const float*)d_in[6];
  const float* b1 = (const float*)d_in[7];
  const float* w2 = (const float*)d_in[8];
  const float* b2 = (const float*)d_in[9];
  const float* w3 = (const float*)d_in[10];
  const float* b3 = (const float*)d_in[11];
  float* out = (float*)d_out;

  char* ws = (char*)d_ws;
  float* FM = (float*)ws;                                   // 32 KiB
  float* C = (float*)(ws + 32768);                          // 16 MiB
  float* h1 = (float*)(ws + 32768 + (size_t)BB * N_OUT * 4);  // 4 MiB
  float* h2 = h1 + (size_t)BB * 256;                        // 2 MiB

  cicdm_fm_kernel<<<N_OUT / 256, 256, 0, stream>>>(fm_vars, FM);
  cicdm_choquet_kernel<<<BB, 256, 0, stream>>>(stu_id, q_idx, emb, FM, C);
  // h1 = relu(C @ w1^T + b1)   : M=4096, N=256,  K=1024
  cicdm_gemm_kernel<64, 32, 32, 4, 2, 0>
      <<<dim3(256 / 32, BB / 64), 256, 0, stream>>>(C, w1, b1, h1, BB, 256, 1024);
  // h2 = relu(h1 @ w2^T + b2)  : M=4096, N=128,  K=256
  cicdm_gemm_kernel<32, 32, 32, 2, 2, 0>
      <<<dim3(128 / 32, BB / 32), 256, 0, stream>>>(h1, w2, b2, h2, BB, 128, 256);
  // out = sigmoid(h2 @ w3^T + b3) : M=4096, N=1024, K=128
  cicdm_gemm_kernel<64, 64, 32, 4, 4, 1>
      <<<dim3(N_OUT / 64, BB / 64), 256, 0, stream>>>(h2, w3, b3, out, BB, N_OUT, 128);
}

// Round 3
// 153.370 us; speedup vs baseline: 1.3386x; 1.3386x over previous
//
#include <hip/hip_runtime.h>
#include <math.h>

#define S_N   100000
#define K_N   30
#define N_OUT 1024
#define BB    4096

typedef unsigned short ushort_t;
typedef __attribute__((ext_vector_type(8))) short bf16x8;
typedef __attribute__((ext_vector_type(4))) float f32x4;

#define GLOBAL_AS(p) ((const __attribute__((address_space(1))) void*)(p))
#define LDS_AS(p)    ((__attribute__((address_space(3))) void*)(p))

__device__ __forceinline__ ushort_t f2bf(float x) {
  union { float f; unsigned u; } a; a.f = x;
  unsigned r = a.u + 0x7FFFu + ((a.u >> 16) & 1u);
  return (ushort_t)(r >> 16);
}
__device__ __forceinline__ float bf2f(ushort_t h) {
  union { float f; unsigned u; } a; a.u = ((unsigned)h) << 16;
  return a.f;
}

// ---------------------------------------------------------------------------
// FM = min(chi-derived 7-vector, 1).T   (1024 x 7, padded to 8) [f32]
// ---------------------------------------------------------------------------
__global__ __launch_bounds__(256) void cicdm_fm_kernel(
    const float* __restrict__ fm_vars, float* __restrict__ FM) {
  int n = blockIdx.x * 256 + threadIdx.x;
  if (n >= N_OUT) return;
  float c0 = fabsf(fm_vars[0 * N_OUT + n]);
  float c1 = fabsf(fm_vars[1 * N_OUT + n]);
  float c2 = fabsf(fm_vars[2 * N_OUT + n]);
  float c3 = fabsf(fm_vars[3 * N_OUT + n]);
  float c4 = fabsf(fm_vars[4 * N_OUT + n]);
  float c5 = fabsf(fm_vars[5 * N_OUT + n]);
  float f0 = c0, f1 = c1;
  float f2 = fmaxf(f0, f1) + c2;
  float f3 = c3;
  float f4 = fmaxf(f3, f0) + c4;
  float f5 = fmaxf(f3, f1) + c5;
  FM[n * 8 + 0] = fminf(f0, 1.f);
  FM[n * 8 + 1] = fminf(f1, 1.f);
  FM[n * 8 + 2] = fminf(f2, 1.f);
  FM[n * 8 + 3] = fminf(f3, 1.f);
  FM[n * 8 + 4] = fminf(f4, 1.f);
  FM[n * 8 + 5] = fminf(f5, 1.f);
  FM[n * 8 + 6] = 1.f;
  FM[n * 8 + 7] = 0.f;
}

// ---------------------------------------------------------------------------
// Split f32 matrix into bf16 hi/lo pair (grid-stride).
// ---------------------------------------------------------------------------
__global__ __launch_bounds__(256) void cicdm_split_kernel(
    const float* __restrict__ w, ushort_t* __restrict__ hi,
    ushort_t* __restrict__ lo, int n) {
  for (int i = blockIdx.x * 256 + threadIdx.x; i < n; i += gridDim.x * 256) {
    float v = w[i];
    ushort_t h = f2bf(v);
    hi[i] = h;
    lo[i] = f2bf(v - bf2f(h));
  }
}

// ---------------------------------------------------------------------------
// Fused gather + sigmoid + stable-3-sort Choquet; emits C as bf16 hi/lo.
// ---------------------------------------------------------------------------
__global__ __launch_bounds__(256) void cicdm_choquet_kernel(
    const int* __restrict__ stu_id, const int* __restrict__ q_idx,
    const float* __restrict__ emb, const float* __restrict__ FM,
    ushort_t* __restrict__ Chi, ushort_t* __restrict__ Clo) {
  __shared__ float s[K_N];
  const int b = blockIdx.x;
  const int tid = threadIdx.x;
  if (tid < K_N) {
    float x = emb[(long)stu_id[b] * K_N + tid];
    s[tid] = 1.f / (1.f + expf(-x));
  }
  __syncthreads();
  for (int n = tid; n < N_OUT; n += 256) {
    int q0 = q_idx[n * 3 + 0];
    int q1 = q_idx[n * 3 + 1];
    int q2 = q_idx[n * 3 + 2];
    float v0 = s[q0], v1 = s[q1], v2 = s[q2];
    bool c01 = v1 > v0, c02 = v2 > v0, c12 = v2 > v1;
    int r0 = (int)c01 + (int)c02;
    int r1 = (int)(!c01) + (int)c12;
    int p0 = (r0 == 0) ? 0 : ((r1 == 0) ? 1 : 2);
    int p1 = (r0 == 1) ? 0 : ((r1 == 1) ? 1 : 2);
    int p2 = 3 - p0 - p1;
    float sv0 = (p0 == 0) ? v0 : ((p0 == 1) ? v1 : v2);
    float sv1 = (p1 == 0) ? v0 : ((p1 == 1) ? v1 : v2);
    float sv2 = (p2 == 0) ? v0 : ((p2 == 1) ? v1 : v2);
    int o0 = (1 << p0) - 1;
    int o1 = (1 << p0) + (1 << p1) - 1;
    float fm0 = FM[n * 8 + o0];
    float fm1 = FM[n * 8 + o1];
    float cval = (sv0 - sv1) * fm0 + (sv1 - sv2) * fm1 + sv2;
    ushort_t h = f2bf(cval);
    Chi[(long)b * N_OUT + n] = h;
    Clo[(long)b * N_OUT + n] = f2bf(cval - bf2f(h));
  }
}

// ---------------------------------------------------------------------------
// Split-bf16 MFMA GEMM: out = act(A[M][K] @ W[N][K]^T + bias)
//   A,W given as bf16 hi/lo pairs (row-major).
//   acc += ah*wh + ah*wl + al*wh   (error ~2^-17)
// EPI 0: relu, emit bf16 hi/lo (next layer operand).  EPI 1: sigmoid f32.
// Wave = 64 lanes; block = WGM*WGN waves. 16x16x32 MFMA fragments.
// LDS k-tile = 32; physical chunk swizzle pc=(c+(row>>1))&3 keeps
// ds_read_b128 column reads at 2-way (free) bank aliasing; the inverse
// permutation is applied on the global_load_lds SOURCE address (rule #21).
// ---------------------------------------------------------------------------
template <int BM, int BN, int WGM, int WGN, int EPI>
__global__ __launch_bounds__(WGM * WGN * 64) void cicdm_mfma_gemm(
    const ushort_t* __restrict__ Ah, const ushort_t* __restrict__ Al,
    const ushort_t* __restrict__ Wh, const ushort_t* __restrict__ Wl,
    const float* __restrict__ bias, ushort_t* __restrict__ outH,
    ushort_t* __restrict__ outL, float* __restrict__ outF,
    int M, int N, int K) {
  constexpr int NT = WGM * WGN * 64;
  constexpr int WTM = BM / WGM, WTN = BN / WGN;
  constexpr int FMr = WTM / 16, FNr = WTN / 16;
  static_assert((BM * 4) % NT == 0 && (BN * 4) % NT == 0, "stage divisibility");

  __shared__ __align__(16) ushort_t smem[(BM + BN) * 64];
  ushort_t* sAh = smem;
  ushort_t* sAl = smem + BM * 32;
  ushort_t* sBh = smem + BM * 64;
  ushort_t* sBl = smem + BM * 64 + BN * 32;

  const int tid = threadIdx.x;
  const int lane = tid & 63;
  const int wid = tid >> 6;
  const int wr = wid / WGN, wc = wid % WGN;
  const int bm = blockIdx.y * BM;
  const int bn = blockIdx.x * BN;
  const int lrow = lane & 15, lc = lane >> 4;

  f32x4 acc[FMr][FNr] = {};

  for (int k0 = 0; k0 < K; k0 += 32) {
    // ---- stage A (hi+lo) ----
#pragma unroll
    for (int it = 0; it < (BM * 4) / NT; ++it) {
      int u = it * NT + tid;
      int row = u >> 2, cp = u & 3;
      int c = (cp - (row >> 1)) & 3;  // inverse swizzle on source
      size_t g = (size_t)(bm + row) * K + k0 + c * 8;
      ushort_t* lb = sAh + (size_t)(it * NT + (wid << 6)) * 8;  // wave-uniform
      __builtin_amdgcn_global_load_lds(GLOBAL_AS(Ah + g), LDS_AS(lb), 16, 0, 0);
      ushort_t* lb2 = sAl + (size_t)(it * NT + (wid << 6)) * 8;
      __builtin_amdgcn_global_load_lds(GLOBAL_AS(Al + g), LDS_AS(lb2), 16, 0, 0);
    }
    // ---- stage W (hi+lo) ----
#pragma unroll
    for (int it = 0; it < (BN * 4) / NT; ++it) {
      int u = it * NT + tid;
      int row = u >> 2, cp = u & 3;
      int c = (cp - (row >> 1)) & 3;
      size_t g = (size_t)(bn + row) * K + k0 + c * 8;
      ushort_t* lb = sBh + (size_t)(it * NT + (wid << 6)) * 8;
      __builtin_amdgcn_global_load_lds(GLOBAL_AS(Wh + g), LDS_AS(lb), 16, 0, 0);
      ushort_t* lb2 = sBl + (size_t)(it * NT + (wid << 6)) * 8;
      __builtin_amdgcn_global_load_lds(GLOBAL_AS(Wl + g), LDS_AS(lb2), 16, 0, 0);
    }
    __syncthreads();  // compiler drains vmcnt before barrier

    bf16x8 fah[FMr], fal[FMr], fbh[FNr], fbl[FNr];
#pragma unroll
    for (int mi = 0; mi < FMr; ++mi) {
      int r = wr * WTM + mi * 16 + lrow;
      int pc = (lc + (r >> 1)) & 3;  // swizzled read
      fah[mi] = *(const bf16x8*)(sAh + r * 32 + pc * 8);
      fal[mi] = *(const bf16x8*)(sAl + r * 32 + pc * 8);
    }
#pragma unroll
    for (int ni = 0; ni < FNr; ++ni) {
      int r = wc * WTN + ni * 16 + lrow;
      int pc = (lc + (r >> 1)) & 3;
      fbh[ni] = *(const bf16x8*)(sBh + r * 32 + pc * 8);
      fbl[ni] = *(const bf16x8*)(sBl + r * 32 + pc * 8);
    }
#pragma unroll
    for (int mi = 0; mi < FMr; ++mi)
#pragma unroll
      for (int ni = 0; ni < FNr; ++ni) {
        acc[mi][ni] = __builtin_amdgcn_mfma_f32_16x16x32_bf16(
            fah[mi], fbh[ni], acc[mi][ni], 0, 0, 0);
        acc[mi][ni] = __builtin_amdgcn_mfma_f32_16x16x32_bf16(
            fah[mi], fbl[ni], acc[mi][ni], 0, 0, 0);
        acc[mi][ni] = __builtin_amdgcn_mfma_f32_16x16x32_bf16(
            fal[mi], fbh[ni], acc[mi][ni], 0, 0, 0);
      }
    __syncthreads();
  }

  // ---- epilogue: D col=lane&15, row=(lane>>4)*4+reg  [m89-verified] ----
#pragma unroll
  for (int mi = 0; mi < FMr; ++mi) {
#pragma unroll
    for (int ni = 0; ni < FNr; ++ni) {
      int col = bn + wc * WTN + ni * 16 + lrow;
      float bv = bias[col];
#pragma unroll
      for (int r = 0; r < 4; ++r) {
        int row = bm + wr * WTM + mi * 16 + lc * 4 + r;
        float v = acc[mi][ni][r] + bv;
        if (EPI == 0) {
          v = fmaxf(v, 0.f);
          ushort_t h = f2bf(v);
          outH[(size_t)row * N + col] = h;
          outL[(size_t)row * N + col] = f2bf(v - bf2f(h));
        } else {
          outF[(size_t)row * N + col] = 1.f / (1.f + expf(-v));
        }
      }
    }
  }
}

// ---------------------------------------------------------------------------
extern "C" void kernel_launch(void* const* d_in, const int* in_sizes, int n_in,
                              void* d_out, int out_size, void* d_ws,
                              size_t ws_size, hipStream_t stream) {
  const int* stu_id = (const int*)d_in[0];
  const int* q_idx = (const int*)d_in[3];
  const float* emb = (const float*)d_in[4];
  const float* fm_vars = (const float*)d_in[5];
  const float* w1 = (const float*)d_in[6];
  const float* b1 = (const float*)d_in[7];
  const float* w2 = (const float*)d_in[8];
  const float* b2 = (const float*)d_in[9];
  const float* w3 = (const float*)d_in[10];
  const float* b3 = (const float*)d_in[11];
  float* out = (float*)d_out;

  char* ws = (char*)d_ws;
  size_t off = 0;
  auto alloc = [&](size_t bytes) { void* p = ws + off; off += (bytes + 255) & ~(size_t)255; return p; };
  float*    FM  = (float*)alloc(N_OUT * 8 * 4);
  ushort_t* Chi = (ushort_t*)alloc((size_t)BB * N_OUT * 2);
  ushort_t* Clo = (ushort_t*)alloc((size_t)BB * N_OUT * 2);
  ushort_t* w1h = (ushort_t*)alloc(256 * N_OUT * 2);
  ushort_t* w1l = (ushort_t*)alloc(256 * N_OUT * 2);
  ushort_t* w2h = (ushort_t*)alloc(128 * 256 * 2);
  ushort_t* w2l = (ushort_t*)alloc(128 * 256 * 2);
  ushort_t* w3h = (ushort_t*)alloc(N_OUT * 128 * 2);
  ushort_t* w3l = (ushort_t*)alloc(N_OUT * 128 * 2);
  ushort_t* h1h = (ushort_t*)alloc((size_t)BB * 256 * 2);
  ushort_t* h1l = (ushort_t*)alloc((size_t)BB * 256 * 2);
  ushort_t* h2h = (ushort_t*)alloc((size_t)BB * 128 * 2);
  ushort_t* h2l = (ushort_t*)alloc((size_t)BB * 128 * 2);

  cicdm_fm_kernel<<<N_OUT / 256, 256, 0, stream>>>(fm_vars, FM);
  cicdm_split_kernel<<<1024, 256, 0, stream>>>(w1, w1h, w1l, 256 * N_OUT);
  cicdm_split_kernel<<<128, 256, 0, stream>>>(w2, w2h, w2l, 128 * 256);
  cicdm_split_kernel<<<512, 256, 0, stream>>>(w3, w3h, w3l, N_OUT * 128);
  cicdm_choquet_kernel<<<BB, 256, 0, stream>>>(stu_id, q_idx, emb, FM, Chi, Clo);

  // GEMM1: h1 = relu(C @ w1^T + b1)   M=4096 N=256 K=1024
  cicdm_mfma_gemm<64, 64, 2, 2, 0>
      <<<dim3(256 / 64, BB / 64), 256, 0, stream>>>(
          Chi, Clo, w1h, w1l, b1, h1h, h1l, nullptr, BB, 256, N_OUT);
  // GEMM2: h2 = relu(h1 @ w2^T + b2)  M=4096 N=128 K=256
  cicdm_mfma_gemm<64, 64, 2, 2, 0>
      <<<dim3(128 / 64, BB / 64), 256, 0, stream>>>(
          h1h, h1l, w2h, w2l, b2, h2h, h2l, nullptr, BB, 128, 256);
  // GEMM3: out = sigmoid(h2 @ w3^T + b3)  M=4096 N=1024 K=128
  cicdm_mfma_gemm<64, 128, 2, 2, 1>
      <<<dim3(N_OUT / 128, BB / 64), 256, 0, stream>>>(
          h2h, h2l, w3h, w3l, b3, nullptr, nullptr, out, BB, N_OUT, 128);
}

// Round 6
// 127.986 us; speedup vs baseline: 1.6041x; 1.1983x over previous
//
#include <hip/hip_runtime.h>
#include <math.h>

#define K_N   30
#define N_OUT 1024
#define BB    4096

typedef unsigned short ushort_t;
typedef __attribute__((ext_vector_type(8))) short bf16x8;
typedef __attribute__((ext_vector_type(4))) float f32x4;
typedef __attribute__((ext_vector_type(4))) int int4v;
typedef __attribute__((ext_vector_type(4))) float float4v;
typedef __attribute__((ext_vector_type(4))) short short4v;

#define GLOBAL_AS(p) ((const __attribute__((address_space(1))) void*)(p))
#define LDS_AS(p)    ((__attribute__((address_space(3))) void*)(p))

__device__ __forceinline__ ushort_t f2bf(float x) {
  union { float f; unsigned u; } a; a.f = x;
  unsigned r = a.u + 0x7FFFu + ((a.u >> 16) & 1u);
  return (ushort_t)(r >> 16);
}
__device__ __forceinline__ float bf2f(ushort_t h) {
  union { float f; unsigned u; } a; a.u = ((unsigned)h) << 16;
  return a.f;
}

// ---------------------------------------------------------------------------
// Fused: weight hi/lo split (side-job: 104 elems/block covers all weights) +
// gather + sigmoid + inline-FM + stable-3-sort Choquet -> C as bf16 hi/lo.
// One block per batch row; thread t handles n = 4t..4t+3.
// ---------------------------------------------------------------------------
__global__ __launch_bounds__(256) void cicdm_choquet_split(
    const int* __restrict__ stu_id, const int* __restrict__ q_idx,
    const float* __restrict__ emb, const float* __restrict__ fm_vars,
    const float* __restrict__ w1, const float* __restrict__ w2,
    const float* __restrict__ w3, ushort_t* __restrict__ Chi,
    ushort_t* __restrict__ Clo, ushort_t* __restrict__ w1h,
    ushort_t* __restrict__ w1l, ushort_t* __restrict__ w2h,
    ushort_t* __restrict__ w2l, ushort_t* __restrict__ w3h,
    ushort_t* __restrict__ w3l) {
  __shared__ float s[K_N];
  const int b = blockIdx.x;
  const int tid = threadIdx.x;

  // ---- weight split side-job: 4096 blocks x 104 = 425984 = |w1|+|w2|+|w3|
  if (tid < 104) {
    int idx = b * 104 + tid;
    float v;
    ushort_t *ph, *pl;
    int off;
    if (idx < 262144) {            // w1: 256x1024
      off = idx; v = w1[off]; ph = w1h; pl = w1l;
    } else if (idx < 294912) {     // w2: 128x256
      off = idx - 262144; v = w2[off]; ph = w2h; pl = w2l;
    } else {                       // w3: 1024x128
      off = idx - 294912; v = w3[off]; ph = w3h; pl = w3l;
    }
    ushort_t h = f2bf(v);
    ph[off] = h;
    pl[off] = f2bf(v - bf2f(h));
  }

  if (tid < K_N) {
    float x = emb[(long)stu_id[b] * K_N + tid];
    s[tid] = 1.f / (1.f + expf(-x));
  }
  __syncthreads();

  const int n0 = tid * 4;
  int qs[12];
  *(int4v*)(qs + 0) = *(const int4v*)(q_idx + n0 * 3 + 0);
  *(int4v*)(qs + 4) = *(const int4v*)(q_idx + n0 * 3 + 4);
  *(int4v*)(qs + 8) = *(const int4v*)(q_idx + n0 * 3 + 8);
  float4v c0v = *(const float4v*)(fm_vars + 0 * N_OUT + n0);
  float4v c1v = *(const float4v*)(fm_vars + 1 * N_OUT + n0);
  float4v c2v = *(const float4v*)(fm_vars + 2 * N_OUT + n0);
  float4v c3v = *(const float4v*)(fm_vars + 3 * N_OUT + n0);
  float4v c4v = *(const float4v*)(fm_vars + 4 * N_OUT + n0);
  float4v c5v = *(const float4v*)(fm_vars + 5 * N_OUT + n0);

  ushort_t hv[4], lv[4];
#pragma unroll
  for (int j = 0; j < 4; ++j) {
    float v0 = s[qs[3 * j]], v1 = s[qs[3 * j + 1]], v2 = s[qs[3 * j + 2]];
    bool c01 = v1 > v0, c02 = v2 > v0, c12 = v2 > v1;
    int r0 = (int)c01 + (int)c02;
    int r1 = (int)(!c01) + (int)c12;
    int p0 = (r0 == 0) ? 0 : ((r1 == 0) ? 1 : 2);
    int p1 = (r0 == 1) ? 0 : ((r1 == 1) ? 1 : 2);
    int p2 = 3 - p0 - p1;
    float sv0 = (p0 == 0) ? v0 : ((p0 == 1) ? v1 : v2);
    float sv1 = (p1 == 0) ? v0 : ((p1 == 1) ? v1 : v2);
    float sv2 = (p2 == 0) ? v0 : ((p2 == 1) ? v1 : v2);
    // inline FM (reference _chi_fm), only the two entries we need
    float f0 = fabsf(c0v[j]), f1 = fabsf(c1v[j]);
    float f2 = fmaxf(f0, f1) + fabsf(c2v[j]);
    float f3 = fabsf(c3v[j]);
    float f4 = fmaxf(f3, f0) + fabsf(c4v[j]);
    float f5 = fmaxf(f3, f1) + fabsf(c5v[j]);
    // o0 = 2^p0-1 in {0,1,3}; o1 = 2^p0+2^p1-1 in {2,4,5} keyed by p2
    float fm0 = (p0 == 0) ? fminf(f0, 1.f)
                          : ((p0 == 1) ? fminf(f1, 1.f) : fminf(f3, 1.f));
    float fm1 = (p2 == 2) ? fminf(f2, 1.f)
                          : ((p2 == 1) ? fminf(f4, 1.f) : fminf(f5, 1.f));
    float cval = (sv0 - sv1) * fm0 + (sv1 - sv2) * fm1 + sv2;
    ushort_t h = f2bf(cval);
    hv[j] = h;
    lv[j] = f2bf(cval - bf2f(h));
  }
  short4v H, L;
  H[0] = (short)hv[0]; H[1] = (short)hv[1]; H[2] = (short)hv[2]; H[3] = (short)hv[3];
  L[0] = (short)lv[0]; L[1] = (short)lv[1]; L[2] = (short)lv[2]; L[3] = (short)lv[3];
  *(short4v*)(Chi + (size_t)b * N_OUT + n0) = H;
  *(short4v*)(Clo + (size_t)b * N_OUT + n0) = L;
}

// ---------------------------------------------------------------------------
// Split-bf16 MFMA GEMM, 64x64 tile, BK=64, double-buffered LDS, 2-phase
// pipeline (catalog T3-minimum): STAGE(next) issued BEFORE compute(cur);
// single vmcnt(0)+s_barrier per k-step so next-tile loads fly under compute.
// XOR-8 swizzle (pc = c ^ (row&7)) -> 2-way (free) LDS bank aliasing on
// ds_read_b128; inverse swizzle applied on global_load_lds SOURCE (rule #21).
// acc += ah*wh + ah*wl + al*wh (split-bf16, rel err ~2^-17).
// EPI 0: relu -> bf16 hi/lo.  EPI 1: sigmoid -> f32.
// ---------------------------------------------------------------------------
template <int EPI>
__global__ __launch_bounds__(256) void cicdm_gemm64(
    const ushort_t* __restrict__ Ah, const ushort_t* __restrict__ Al,
    const ushort_t* __restrict__ Wh, const ushort_t* __restrict__ Wl,
    const float* __restrict__ bias, ushort_t* __restrict__ outH,
    ushort_t* __restrict__ outL, float* __restrict__ outF, int N, int K) {
  constexpr int BM = 64, BN = 64, BK = 64, CH = 8;
  constexpr int REG = BM * BK;       // ushorts per region
  constexpr int BUF = 4 * REG;       // Ah,Al,Wh,Wl regions = 16384 ushorts
  __shared__ __align__(16) ushort_t smem[2 * BUF];  // 64 KiB

  const int tid = threadIdx.x;
  const int lane = tid & 63;
  const int wid = tid >> 6;
  const int wr = wid >> 1, wc = wid & 1;
  const int bm = blockIdx.y * BM;
  const int bn = blockIdx.x * BN;
  const int lrow = lane & 15, lc = lane >> 4;

  auto STAGE = [&](int d, int k0) {
#pragma unroll
    for (int it = 0; it < 2; ++it) {  // BM*CH / 256 = 2
      int u = it * 256 + tid;
      int row = u >> 3, cp = u & 7;
      int c = cp ^ (row & 7);  // inverse swizzle on source
      size_t ga = (size_t)(bm + row) * K + k0 + c * 8;
      size_t gw = (size_t)(bn + row) * K + k0 + c * 8;
      int lofs = (it * 256 + (wid << 6)) * 8;  // wave-uniform
      ushort_t* base = smem + d * BUF;
      __builtin_amdgcn_global_load_lds(GLOBAL_AS(Ah + ga),
                                       LDS_AS(base + lofs), 16, 0, 0);
      __builtin_amdgcn_global_load_lds(GLOBAL_AS(Al + ga),
                                       LDS_AS(base + REG + lofs), 16, 0, 0);
      __builtin_amdgcn_global_load_lds(GLOBAL_AS(Wh + gw),
                                       LDS_AS(base + 2 * REG + lofs), 16, 0, 0);
      __builtin_amdgcn_global_load_lds(GLOBAL_AS(Wl + gw),
                                       LDS_AS(base + 3 * REG + lofs), 16, 0, 0);
    }
  };

  f32x4 acc[2][2] = {};
  const int rA[2] = {wr * 32 + lrow, wr * 32 + lrow + 16};
  const int rB[2] = {wc * 32 + lrow, wc * 32 + lrow + 16};

  auto COMPUTE = [&](int d) {
    ushort_t* base = smem + d * BUF;
#pragma unroll
    for (int ks = 0; ks < 2; ++ks) {
      bf16x8 fah[2], fal[2], fbh[2], fbl[2];
#pragma unroll
      for (int i = 0; i < 2; ++i) {
        int pcA = (ks * 4 + lc) ^ (rA[i] & 7);
        int pcB = (ks * 4 + lc) ^ (rB[i] & 7);
        fah[i] = *(const bf16x8*)(base + (rA[i] * CH + pcA) * 8);
        fal[i] = *(const bf16x8*)(base + REG + (rA[i] * CH + pcA) * 8);
        fbh[i] = *(const bf16x8*)(base + 2 * REG + (rB[i] * CH + pcB) * 8);
        fbl[i] = *(const bf16x8*)(base + 3 * REG + (rB[i] * CH + pcB) * 8);
      }
#pragma unroll
      for (int mi = 0; mi < 2; ++mi)
#pragma unroll
        for (int ni = 0; ni < 2; ++ni) {
          acc[mi][ni] = __builtin_amdgcn_mfma_f32_16x16x32_bf16(
              fah[mi], fbh[ni], acc[mi][ni], 0, 0, 0);
          acc[mi][ni] = __builtin_amdgcn_mfma_f32_16x16x32_bf16(
              fah[mi], fbl[ni], acc[mi][ni], 0, 0, 0);
          acc[mi][ni] = __builtin_amdgcn_mfma_f32_16x16x32_bf16(
              fal[mi], fbh[ni], acc[mi][ni], 0, 0, 0);
        }
    }
  };

  // ---- 2-phase pipeline ----
  STAGE(0, 0);
  asm volatile("s_waitcnt vmcnt(0)" ::: "memory");
  __builtin_amdgcn_s_barrier();
  const int nst = K >> 6;
  for (int t = 0; t < nst; ++t) {
    int cur = t & 1;
    if (t + 1 < nst) STAGE(cur ^ 1, (t + 1) << 6);
    COMPUTE(cur);
    asm volatile("s_waitcnt vmcnt(0)" ::: "memory");
    __builtin_amdgcn_s_barrier();
  }

  // ---- epilogue: D col=lane&15, row=(lane>>4)*4+reg [m89-verified] ----
#pragma unroll
  for (int mi = 0; mi < 2; ++mi) {
#pragma unroll
    for (int ni = 0; ni < 2; ++ni) {
      int col = bn + wc * 32 + ni * 16 + lrow;
      float bv = bias[col];
#pragma unroll
      for (int r = 0; r < 4; ++r) {
        int row = bm + wr * 32 + mi * 16 + lc * 4 + r;
        float v = acc[mi][ni][r] + bv;
        if (EPI == 0) {
          v = fmaxf(v, 0.f);
          ushort_t h = f2bf(v);
          outH[(size_t)row * N + col] = h;
          outL[(size_t)row * N + col] = f2bf(v - bf2f(h));
        } else {
          outF[(size_t)row * N + col] = 1.f / (1.f + expf(-v));
        }
      }
    }
  }
}

// ---------------------------------------------------------------------------
extern "C" void kernel_launch(void* const* d_in, const int* in_sizes, int n_in,
                              void* d_out, int out_size, void* d_ws,
                              size_t ws_size, hipStream_t stream) {
  const int* stu_id = (const int*)d_in[0];
  const int* q_idx = (const int*)d_in[3];
  const float* emb = (const float*)d_in[4];
  const float* fm_vars = (const float*)d_in[5];
  const float* w1 = (const float*)d_in[6];
  const float* b1 = (const float*)d_in[7];
  const float* w2 = (const float*)d_in[8];
  const float* b2 = (const float*)d_in[9];
  const float* w3 = (const float*)d_in[10];
  const float* b3 = (const float*)d_in[11];
  float* out = (float*)d_out;

  char* ws = (char*)d_ws;
  size_t off = 0;
  auto alloc = [&](size_t bytes) {
    void* p = ws + off;
    off += (bytes + 255) & ~(size_t)255;
    return p;
  };
  ushort_t* Chi = (ushort_t*)alloc((size_t)BB * N_OUT * 2);
  ushort_t* Clo = (ushort_t*)alloc((size_t)BB * N_OUT * 2);
  ushort_t* w1h = (ushort_t*)alloc(256 * N_OUT * 2);
  ushort_t* w1l = (ushort_t*)alloc(256 * N_OUT * 2);
  ushort_t* w2h = (ushort_t*)alloc(128 * 256 * 2);
  ushort_t* w2l = (ushort_t*)alloc(128 * 256 * 2);
  ushort_t* w3h = (ushort_t*)alloc(N_OUT * 128 * 2);
  ushort_t* w3l = (ushort_t*)alloc(N_OUT * 128 * 2);
  ushort_t* h1h = (ushort_t*)alloc((size_t)BB * 256 * 2);
  ushort_t* h1l = (ushort_t*)alloc((size_t)BB * 256 * 2);
  ushort_t* h2h = (ushort_t*)alloc((size_t)BB * 128 * 2);
  ushort_t* h2l = (ushort_t*)alloc((size_t)BB * 128 * 2);

  // 1 fused prep+choquet kernel, then 3 pipelined GEMMs (4 launches total)
  cicdm_choquet_split<<<BB, 256, 0, stream>>>(
      stu_id, q_idx, emb, fm_vars, w1, w2, w3, Chi, Clo, w1h, w1l, w2h, w2l,
      w3h, w3l);

  // GEMM1: h1 = relu(C @ w1^T + b1)   M=4096 N=256 K=1024
  cicdm_gemm64<0><<<dim3(4, 64), 256, 0, stream>>>(
      Chi, Clo, w1h, w1l, b1, h1h, h1l, nullptr, 256, 1024);
  // GEMM2: h2 = relu(h1 @ w2^T + b2)  M=4096 N=128 K=256
  cicdm_gemm64<0><<<dim3(2, 64), 256, 0, stream>>>(
      h1h, h1l, w2h, w2l, b2, h2h, h2l, nullptr, 128, 256);
  // GEMM3: out = sigmoid(h2 @ w3^T + b3)  M=4096 N=1024 K=128
  cicdm_gemm64<1><<<dim3(16, 64), 256, 0, stream>>>(
      h2h, h2l, w3h, w3l, b3, nullptr, nullptr, out, 1024, 128);
}